// Round 12
// baseline (66.794 us; speedup 1.0000x reference)
//
#include <hip/hip_runtime.h>
#include <hip/hip_bf16.h>

typedef __bf16 bf16x8 __attribute__((ext_vector_type(8)));
typedef float f32x4 __attribute__((ext_vector_type(4)));

// Pre-kernel: clusters (128x512 f32) -> bf16 in ws, plus fp32 c2[128].
__global__ __launch_bounds__(64)
void prep_clusters(const float* __restrict__ c, __bf16* __restrict__ cb,
                   float* __restrict__ c2)
{
    const int row = blockIdx.x;     // 0..127
    const int l = threadIdx.x;      // 0..63
    const float* p = c + row * 512 + l * 8;
    f32x4 u0 = *(const f32x4*)p;
    f32x4 u1 = *(const f32x4*)(p + 4);
    bf16x8 v;
    float s = 0.f;
#pragma unroll
    for (int j = 0; j < 4; ++j) {
        v[j]     = (__bf16)u0[j];
        v[4 + j] = (__bf16)u1[j];
        s += u0[j] * u0[j] + u1[j] * u1[j];
    }
    *(bf16x8*)(cb + row * 512 + l * 8) = v;
#pragma unroll
    for (int off = 32; off >= 1; off >>= 1) s += __shfl_xor(s, off);
    if (l == 0) c2[row] = s;
}

// R11 (65.9 us) with a ZERO-REGISTER REORDER: the staging block
// {vmcnt -> DSWRITE(p+1) -> GLOAD(p+2) -> barrier} moves to right after the
// compute loop, and the expensive epilogue (inv, normalize, qt bounce, NT
// stores) moves after it. GLOAD(p+2) is thus outstanding during
// {epilogue(p) + compute(p+1)} — nearly the whole pass — instead of idling
// the memory pipe for the post-arrival ~65% of each pass (R11 delivered
// 6.6 B/cyc/CU of the 10.25 available; this lifts issue duty cycle with no
// VGPR cost, unlike R9's failed 2-G-set attempt). rsx-publish and staging-WAR
// barriers fold into one; still 2 barriers/pass.
__global__ __launch_bounds__(256, 2)
void cluster_q_mfma(const float* __restrict__ x,
                    const __bf16* __restrict__ cb,
                    const float* __restrict__ c2,
                    float* __restrict__ out)
{
    __shared__ float lds[16 * 512];      // one 32 KB tile (16 rows x 512)
    __shared__ float rsx[4][16];         // per-wave partial row sums
    __shared__ float qt[4][16 * 32];     // per-wave q transpose tile (2 KB)

    const int tid = threadIdx.x;
    const int l = tid & 63;
    const int w = tid >> 6;         // wave 0..3: owns cols w*32 .. w*32+31
    const int m = l & 15;           // fragment row (A) / col (B)
    const int g = l >> 4;           // k-group 0..3
    const long brow = (long)blockIdx.x * 256;

    float c2v[2];
#pragma unroll
    for (int nb = 0; nb < 2; ++nb) c2v[nb] = c2[w * 32 + nb * 16 + m];

    // Persistent B: cols w*32+nb*16+m, all 512 k. 32 x b128 loads, 128 VGPRs.
    bf16x8 bR[2][16];
#pragma unroll
    for (int nb = 0; nb < 2; ++nb)
#pragma unroll
        for (int ks = 0; ks < 16; ++ks)
            bR[nb][ks] = *(const bf16x8*)(
                cb + (w * 32 + nb * 16 + m) * 512 + ks * 32 + g * 8);

    // Staging geometry: instr i_ covers tile-row w*4+(i_>>1), half h=i_&1;
    // lane l takes chunk l of the 1KB half (fully linear global read).
    int cow[4];
#pragma unroll
    for (int q = 0; q < 4; ++q)
        cow[q] = (l & 56) + ((l & 7) ^ ((w * 4 + q) & 7));

    // LDS read bases (bytes): row m, chunk (ks*8 + (2g|2g+1)^(m&7)).
    const int rbo0 = m * 2048 + (((2 * g)     ^ (m & 7)) * 16);
    const int rbo1 = m * 2048 + (((2 * g + 1) ^ (m & 7)) * 16);

    // Output read-back geometry: 2 instructions of 8 rows x 8 chunks.
    const int orow_l = l >> 3;      // row within 8-row half
    const int opos = l & 7;         // 16B chunk position within 32-col piece

    f32x4 G[8];

#define SB __builtin_amdgcn_sched_barrier(0)
#define GLOAD(P)                                                          \
    { _Pragma("unroll")                                                   \
      for (int i_ = 0; i_ < 8; ++i_)                                      \
          G[i_] = *(const f32x4*)(x + (brow + (long)(P) * 16              \
                     + w * 4 + (i_ >> 1)) * 512 + (i_ & 1) * 256 + l * 4); }
#define DSWRITE()                                                         \
    { _Pragma("unroll")                                                   \
      for (int i_ = 0; i_ < 8; ++i_)                                      \
          *(f32x4*)(&lds[(w * 4 + (i_ >> 1)) * 512 + (i_ & 1) * 256       \
                         + cow[i_ >> 1] * 4]) = G[i_]; }

    // Prologue: tile 0 through registers into LDS; loads for tile 1 in flight.
    GLOAD(0);
    asm volatile("s_waitcnt vmcnt(0)" ::: "memory");
    DSWRITE();
    GLOAD(1);
    asm volatile("s_waitcnt lgkmcnt(0)" ::: "memory");
    __builtin_amdgcn_s_barrier();

#pragma unroll 1
    for (int p = 0; p < 16; ++p) {
        // P1: compute pass p from LDS tile.
        f32x4 acc[2] = {f32x4{0.f, 0.f, 0.f, 0.f}, f32x4{0.f, 0.f, 0.f, 0.f}};
        float x2p = 0.f;
        const char* L = (const char*)&lds[0];
#pragma unroll
        for (int ks = 0; ks < 16; ++ks) {
            f32x4 u0 = *(const f32x4*)(L + rbo0 + ks * 128);
            f32x4 u1 = *(const f32x4*)(L + rbo1 + ks * 128);
            bf16x8 aF;
#pragma unroll
            for (int j = 0; j < 4; ++j) {
                aF[j]     = (__bf16)u0[j];
                aF[4 + j] = (__bf16)u1[j];
                x2p += u0[j] * u0[j] + u1[j] * u1[j];
            }
            acc[0] = __builtin_amdgcn_mfma_f32_16x16x32_bf16(aF, bR[0][ks], acc[0], 0, 0, 0);
            acc[1] = __builtin_amdgcn_mfma_f32_16x16x32_bf16(aF, bR[1][ks], acc[1], 0, 0, 0);
        }

        // P2: partial row sums (everything that must precede the fold-barrier).
        x2p += __shfl_xor(x2p, 16);
        x2p += __shfl_xor(x2p, 32);
        float x2r[4], rs[4];
#pragma unroll
        for (int r = 0; r < 4; ++r) {
            x2r[r] = __shfl(x2p, g * 4 + r);
            rs[r] = 0.f;
        }
#pragma unroll
        for (int nb = 0; nb < 2; ++nb)
#pragma unroll
            for (int r = 0; r < 4; ++r) {
                float d2 = fmaxf(x2r[r] + c2v[nb] - 2.f * acc[nb][r], 0.f);
                float qv = __builtin_amdgcn_rcpf(1.f + d2);  // ALPHA=1
                acc[nb][r] = qv;
                rs[r] += qv;
            }
#pragma unroll
        for (int r = 0; r < 4; ++r) {
            rs[r] += __shfl_xor(rs[r], 1);
            rs[r] += __shfl_xor(rs[r], 2);
            rs[r] += __shfl_xor(rs[r], 4);
            rs[r] += __shfl_xor(rs[r], 8);
        }
        if (m == 0) {
#pragma unroll
            for (int r = 0; r < 4; ++r) rsx[w][g * 4 + r] = rs[r];
        }

        // BARRIER-1 (folded): tile-p reads done by all waves AND rsx published.
        asm volatile("s_waitcnt lgkmcnt(0)" ::: "memory");
        __builtin_amdgcn_s_barrier();
        SB;

        // P3: staging FIRST — land tile p+1, issue loads for p+2 immediately.
        // vmcnt(2): outstanding = 8 loads(p+1) [oldest] + 2 NT stores(p-1)
        // [newest] -> drains exactly the loads.
        if (p < 15) {
            asm volatile("s_waitcnt vmcnt(2)" ::: "memory");
            SB;
            DSWRITE();
            if (p < 14) { GLOAD(p + 2); }
            asm volatile("s_waitcnt lgkmcnt(0)" ::: "memory");
            __builtin_amdgcn_s_barrier();  // BARRIER-2: tile p+1 visible
            SB;
        }

        // P4: epilogue — runs with loads(p+2) in flight. inv from rsx,
        // normalize, qt bounce (wave-private), 2 full-line NT stores.
        float inv[4];
#pragma unroll
        for (int r = 0; r < 4; ++r) {
            const int row16 = g * 4 + r;
            inv[r] = __builtin_amdgcn_rcpf(
                rsx[0][row16] + rsx[1][row16] + rsx[2][row16] + rsx[3][row16]);
        }
#pragma unroll
        for (int r = 0; r < 4; ++r) {
            const int row16 = g * 4 + r;
#pragma unroll
            for (int nb = 0; nb < 2; ++nb) {
                const int chunk = nb * 4 + (m >> 2);
                qt[w][row16 * 32 + ((chunk ^ (row16 & 7)) * 4) + (m & 3)] =
                    acc[nb][r] * inv[r];
            }
        }
        // wave-private RAW on qt: compiler inserts the needed lgkmcnt.
        const long obase = brow + p * 16;
#pragma unroll
        for (int h = 0; h < 2; ++h) {
            const int row16 = h * 8 + orow_l;
            f32x4 v = *(const f32x4*)&qt[w][row16 * 32 +
                                            ((opos ^ (row16 & 7)) * 4)];
            __builtin_nontemporal_store(
                v, (f32x4*)(out + (obase + row16) * 128 + w * 32 + opos * 4));
        }
        SB;
    }
#undef GLOAD
#undef DSWRITE
#undef SB
}

extern "C" void kernel_launch(void* const* d_in, const int* in_sizes, int n_in,
                              void* d_out, int out_size, void* d_ws, size_t ws_size,
                              hipStream_t stream)
{
    const float* x = (const float*)d_in[0];
    const float* c = (const float*)d_in[1];
    float* out = (float*)d_out;

    float*  c2ws = (float*)d_ws;                        // 128 floats
    __bf16* cbws = (__bf16*)((char*)d_ws + 1024);       // 128x512 bf16 = 128 KB

    hipLaunchKernelGGL(prep_clusters, dim3(128), dim3(64), 0, stream, c, cbws, c2ws);

    const int N = in_sizes[0] / 512;                    // 131072 rows
    dim3 grid(N / 256), block(256);                     // 512 blocks = 2/CU
    hipLaunchKernelGGL(cluster_q_mfma, grid, block, 0, stream, x, cbws, c2ws, out);
}